// Round 1
// baseline (357.686 us; speedup 1.0000x reference)
//
#include <hip/hip_runtime.h>
#include <math.h>

// Problem: x (16,3,1024,1024) fp32 NCHW -> out same shape.
// Pure per-pixel op; channels coupled. Memory-bound target ~64us.

#define HWSZ (1024*1024)          // pixels per image plane
#define NB   16                   // batch
#define NGROUPS ((NB*HWSZ)/4)     // float4 groups total = 4,194,304

__constant__ float c_hp[30] = {
    0.5f, 1.2f, 0.5f, 0.1f, 0.8f,
    0.4f, 1.1f, 0.4f, 0.1f, 0.8f,
    0.3f, 1.0f, 0.3f, 0.1f, 0.9f,
    0.3f, 1.0f, 0.3f, 0.1f, 0.9f,
    0.4f, 1.1f, 0.4f, 0.1f, 0.8f,
    0.5f, 1.2f, 0.5f, 0.1f, 0.8f
};

__device__ __forceinline__ float clamp01(float v) {
    return fminf(fmaxf(v, 0.0f), 1.0f);
}

__device__ __forceinline__ void process_px(float r, float g, float b,
                                           float& ro, float& go, float& bo) {
    // RGB -> YCbCr
    float y  =  0.2126f * r + 0.7152f * g + 0.0722f * b;
    float cb = -0.1146f * r - 0.3854f * g + 0.5f    * b;
    float cr =  0.5f    * r - 0.4542f * g - 0.0458f * b;

    float cb255 = cb * 255.0f;
    float cr255 = cr * 255.0f;
    float chroma = sqrtf(cb255 * cb255 + cr255 * cr255);

    // hue in degrees, [0, 360)
    float hue = atan2f(cr255, cb255) * 57.29577951308232f; // rad->deg
    hue = fmodf(hue + 360.0f, 360.0f);

    float hf = hue * (1.0f / 60.0f);
    int il = (int)floorf(hf);
    il = (il < 0) ? 0 : ((il > 5) ? 5 : il);
    int iu = (il == 5) ? 0 : (il + 1);

    float hue_lower = (float)il * 60.0f;
    float alpha = (hue - hue_lower) * (1.0f / 60.0f);
    // reference's where(hue < hue_lower) branch can't trigger since
    // hue_lower = floor(hue/60)*60 <= hue, but keep the clamp for FP safety
    if (alpha < 0.0f) alpha = (hue + 360.0f - hue_lower) * (1.0f / 60.0f);

    const float* plo = &c_hp[il * 5];
    const float* pup = &c_hp[iu * 5];
    float omα = 1.0f - alpha;
    float a1 = plo[0] * omα + pup[0] * alpha;
    float a2 = plo[1] * omα + pup[1] * alpha;
    float a3 = plo[2] * omα + pup[2] * alpha;
    float a4 = plo[3] * omα + pup[3] * alpha;
    float a5 = plo[4] * omα + pup[4] * alpha;

    // luma log term: log(y255/255 + 1e-6) + 0.1 == log(y + 1e-6) + 0.1
    float llt = logf(y + 1e-6f) + 0.1f;

    float term1 = powf(chroma, a1);
    float term2 = a2 * llt + a3;
    // cw = 1.2 : cw^2 + a5*cw + a5 - 1 = 1.44 + 2.2*a5 - 1
    float term3 = a4 * (1.44f + 1.2f * a5 + a5 - 1.0f);

    float delta_luma = term1 * term2 * term3;
    float yo = clamp01(y + delta_luma * (1.0f / 255.0f));

    float cbo = cb * 1.2f;
    float cro = cr * 1.2f;

    // YCbCr -> RGB
    ro = clamp01(yo + 1.5748f * cro);
    go = clamp01(yo - 0.1873f * cbo - 0.4681f * cro);
    bo = clamp01(yo + 1.8556f * cbo);
}

__global__ __launch_bounds__(256)
void ContrastPreservedChromaEnhancement_69741678952895_kernel(
        const float* __restrict__ x, float* __restrict__ out) {
    int i = blockIdx.x * blockDim.x + threadIdx.x;   // float4-group index
    if (i >= NGROUPS) return;

    int bimg = i >> 18;                 // (i*4) / 2^20
    int p4   = i & ((HWSZ / 4) - 1);    // group within plane
    size_t base = (size_t)bimg * (3ull * HWSZ) + (size_t)p4 * 4ull;

    const float4 R = *reinterpret_cast<const float4*>(x + base);
    const float4 G = *reinterpret_cast<const float4*>(x + base + HWSZ);
    const float4 B = *reinterpret_cast<const float4*>(x + base + 2 * HWSZ);

    float4 Ro, Go, Bo;
    process_px(R.x, G.x, B.x, Ro.x, Go.x, Bo.x);
    process_px(R.y, G.y, B.y, Ro.y, Go.y, Bo.y);
    process_px(R.z, G.z, B.z, Ro.z, Go.z, Bo.z);
    process_px(R.w, G.w, B.w, Ro.w, Go.w, Bo.w);

    *reinterpret_cast<float4*>(out + base)             = Ro;
    *reinterpret_cast<float4*>(out + base + HWSZ)      = Go;
    *reinterpret_cast<float4*>(out + base + 2 * HWSZ)  = Bo;
}

extern "C" void kernel_launch(void* const* d_in, const int* in_sizes, int n_in,
                              void* d_out, int out_size, void* d_ws, size_t ws_size,
                              hipStream_t stream) {
    const float* x = (const float*)d_in[0];
    float* out = (float*)d_out;

    const int block = 256;
    const int grid = NGROUPS / block;   // 4,194,304 / 256 = 16384
    ContrastPreservedChromaEnhancement_69741678952895_kernel
        <<<grid, block, 0, stream>>>(x, out);
}

// Round 2
// 325.402 us; speedup vs baseline: 1.0992x; 1.0992x over previous
//
#include <hip/hip_runtime.h>
#include <math.h>

// x: (16,3,1024,1024) fp32 NCHW -> out same shape. Pure elementwise.
// R2: all libm transcendentals replaced with hw v_log/v_exp/v_rcp + minimax
// atan poly; 6x5 hue-param table replaced by closed-form piecewise-linear
// functions of u=hue/60 (exactly equal to the reference's table lerp):
//   m(u) = clamp(max(2-u, u-3), 0, 2)   -> a1=0.3+0.1m, a2=a1+0.7, a3=a1
//   n(u) = clamp(min(u-1, 4-u), 0, 1)   -> a5=0.8+0.1n ; a4=0.1 const
//   term3 = 0.1*(1.44 + 2.2*a5 - 1) = 0.22 + 0.022*n

#define HWSZ (1024*1024)
#define NB   16
#define NGROUPS ((NB*HWSZ)/4)   // 4,194,304 float4 groups

__device__ __forceinline__ float clamp01(float v) {
    return fminf(fmaxf(v, 0.0f), 1.0f);
}

// minimax odd poly for atan(t), t in [0,1]; max err ~1e-5 rad
__device__ __forceinline__ float atan_poly(float t) {
    float t2 = t * t;
    float p = -0.01172120f;
    p = fmaf(p, t2, 0.05265332f);
    p = fmaf(p, t2, -0.11643287f);
    p = fmaf(p, t2, 0.19354346f);
    p = fmaf(p, t2, -0.33262347f);
    p = fmaf(p, t2, 0.99997726f);
    return p * t;
}

__device__ __forceinline__ void process_px(float r, float g, float b,
                                           float& ro, float& go, float& bo) {
    // RGB -> YCbCr
    float y  = fmaf(0.2126f, r, fmaf(0.7152f, g, 0.0722f * b));
    float cb = fmaf(-0.1146f, r, fmaf(-0.3854f, g, 0.5f * b));
    float cr = fmaf(0.5f, r, fmaf(-0.4542f, g, -0.0458f * b));

    // log2(chroma) = 0.5*log2(cb^2+cr^2) + log2(255)
    float s = fmaf(cb, cb, cr * cr);
    float l2c = fmaf(0.5f, __builtin_amdgcn_logf(s), 7.99435344f);

    // fast atan2(cr, cb) expressed directly in u = hue_deg/60 units
    float ax = fabsf(cb), ay = fabsf(cr);
    float mx = fmaxf(ax, ay), mn = fminf(ax, ay);
    float t = mn * __builtin_amdgcn_rcpf(mx);
    t = (mx > 0.0f) ? t : 0.0f;            // atan2(0,0) -> 0 (matches jnp)
    float u = atan_poly(t) * 0.954929658551372f;   // 3/pi : rad -> u-units
    u = (ay > ax) ? (1.5f - u) : u;        // pi/2 - a
    u = (cb < 0.0f) ? (3.0f - u) : u;      // pi - a
    u = (cr < 0.0f) ? -u : u;              // sign(y)
    u = (u < 0.0f) ? u + 6.0f : u;         // wrap to [0,6)

    // piecewise-linear params (exact table lerp)
    float m = fminf(fmaxf(fmaxf(2.0f - u, u - 3.0f), 0.0f), 2.0f);
    float n = fminf(fmaxf(fminf(u - 1.0f, 4.0f - u), 0.0f), 1.0f);
    float a1 = fmaf(0.1f, m, 0.3f);
    float a2 = a1 + 0.7f;                  // a3 == a1, a4 == 0.1

    // luma log term: ln(y+1e-6)+0.1 = log2(y+1e-6)*ln2 + 0.1
    float llt = fmaf(0.693147181f, __builtin_amdgcn_logf(y + 1e-6f), 0.1f);

    float term1 = __builtin_amdgcn_exp2f(a1 * l2c);   // chroma^a1
    float term2 = fmaf(a2, llt, a1);                  // a2*llt + a3
    float term3 = fmaf(0.022f, n, 0.22f);             // a4*(cw^2+a5*cw+a5-1)

    float delta = term1 * term2 * term3;
    float yo = clamp01(fmaf(delta, 1.0f / 255.0f, y));

    float cbo = cb * 1.2f, cro = cr * 1.2f;
    ro = clamp01(fmaf(1.5748f, cro, yo));
    go = clamp01(fmaf(-0.1873f, cbo, fmaf(-0.4681f, cro, yo)));
    bo = clamp01(fmaf(1.8556f, cbo, yo));
}

__global__ __launch_bounds__(256)
void ContrastPreservedChromaEnhancement_69741678952895_kernel(
        const float* __restrict__ x, float* __restrict__ out) {
    int i = blockIdx.x * blockDim.x + threadIdx.x;   // float4-group index
    if (i >= NGROUPS) return;

    int bimg = i >> 18;                 // (i*4) / 2^20
    int p4   = i & ((HWSZ / 4) - 1);    // group within plane
    size_t base = (size_t)bimg * (3ull * HWSZ) + (size_t)p4 * 4ull;

    const float4 R = *reinterpret_cast<const float4*>(x + base);
    const float4 G = *reinterpret_cast<const float4*>(x + base + HWSZ);
    const float4 B = *reinterpret_cast<const float4*>(x + base + 2 * HWSZ);

    float4 Ro, Go, Bo;
    process_px(R.x, G.x, B.x, Ro.x, Go.x, Bo.x);
    process_px(R.y, G.y, B.y, Ro.y, Go.y, Bo.y);
    process_px(R.z, G.z, B.z, Ro.z, Go.z, Bo.z);
    process_px(R.w, G.w, B.w, Ro.w, Go.w, Bo.w);

    *reinterpret_cast<float4*>(out + base)            = Ro;
    *reinterpret_cast<float4*>(out + base + HWSZ)     = Go;
    *reinterpret_cast<float4*>(out + base + 2 * HWSZ) = Bo;
}

extern "C" void kernel_launch(void* const* d_in, const int* in_sizes, int n_in,
                              void* d_out, int out_size, void* d_ws, size_t ws_size,
                              hipStream_t stream) {
    const float* x = (const float*)d_in[0];
    float* out = (float*)d_out;

    const int block = 256;
    const int grid = NGROUPS / block;   // 16384
    ContrastPreservedChromaEnhancement_69741678952895_kernel
        <<<grid, block, 0, stream>>>(x, out);
}